// Round 2
// baseline (232.622 us; speedup 1.0000x reference)
//
#include <hip/hip_runtime.h>

// Bilinear resample: inputs (B,S,S,C) fp32, offsets (B,S,S,2) fp32 -> out (B,S,S,C)
// B=16, S=128, C=128. Memory-bound gather, near-identity sampling grid.
//
// R1: XCD-aware slab swizzle (blockIdx&7 -> 16-row slab, walk rows innermost so
// vertical corner reuse hits the same XCD's L2 one block later) + nontemporal
// output stores (write-once stream, keep L2 for input lines).

constexpr int S = 128;
constexpr int CVEC = 32;            // C/4 float4 groups per pixel
constexpr int PIX_PER_BLOCK = 8;    // 256 threads / 32 threads-per-pixel
constexpr int NXCD = 8;
constexpr int ROWS_PER_SLAB = S / NXCD;     // 16
constexpr int SEGS = S / PIX_PER_BLOCK;     // 16

typedef float vf4 __attribute__((ext_vector_type(4)));

__global__ __launch_bounds__(256) void resample_kernel(
    const float* __restrict__ offsets,   // (B, S, S, 2)
    const vf4*  __restrict__ inputs4,    // (B, S, S, C/4)
    vf4*        __restrict__ out4)       // (B, S, S, C/4)
{
    const int tid     = threadIdx.x;
    const int lane_c  = tid & 31;        // channel-group (0..31)
    const int pix_blk = tid >> 5;        // pixel within block (0..7)

    // Block swizzle: xcd = slab of 16 rows; within an XCD walk rows innermost
    // (vertical reuse 1 block apart, same-XCD L2), then column segments, then batch.
    const int x   = blockIdx.x;
    const int xcd = x & (NXCD - 1);
    const int g   = x >> 3;
    const int r   = g & (ROWS_PER_SLAB - 1);
    const int seg = (g >> 4) & (SEGS - 1);
    const int b   = g >> 8;

    const int i = xcd * ROWS_PER_SLAB + r;
    const int j = seg * PIX_PER_BLOCK + pix_blk;
    const int pix = (b * S + i) * S + j;

    // Per-pixel coords & weights (redundant across the 32 lanes of this pixel)
    const float oy = offsets[pix * 2 + 0];
    const float ox = offsets[pix * 2 + 1];
    float y = fminf(fmaxf((float)i + oy, 0.0f), (float)(S - 1));
    float xx = fminf(fmaxf((float)j + ox, 0.0f), (float)(S - 1));

    const float y0f = floorf(y);
    const float x0f = floorf(xx);
    const int y0 = (int)y0f;
    const int x0 = (int)x0f;
    const int y1 = (int)ceilf(y);        // == y0 when integral (matches reference)
    const int x1 = (int)ceilf(xx);
    const float fy = y - y0f;            // row fraction
    const float fx = xx - x0f;           // col fraction

    const int base = (b * S * S) * CVEC + lane_c;
    const int r0 = base + y0 * (S * CVEC);
    const int r1 = base + y1 * (S * CVEC);

    const vf4 v00 = inputs4[r0 + x0 * CVEC];
    const vf4 v01 = inputs4[r0 + x1 * CVEC];
    const vf4 v10 = inputs4[r1 + x0 * CVEC];
    const vf4 v11 = inputs4[r1 + x1 * CVEC];

    // Reference order: lerp along x, then along y.
    const vf4 vt = v00 + (v01 - v00) * fx;
    const vf4 vb = v10 + (v11 - v10) * fx;
    const vf4 o  = vt + (vb - vt) * fy;

    __builtin_nontemporal_store(o, &out4[(long long)pix * CVEC + lane_c]);
}

extern "C" void kernel_launch(void* const* d_in, const int* in_sizes, int n_in,
                              void* d_out, int out_size, void* d_ws, size_t ws_size,
                              hipStream_t stream) {
    const float* offsets = (const float*)d_in[0];
    const vf4*   inputs4 = (const vf4*)d_in[1];
    vf4*         out4    = (vf4*)d_out;

    const int B = in_sizes[0] / (S * S * 2);   // = 16
    const int total_pix = B * S * S;           // 262144
    const int blocks = total_pix / PIX_PER_BLOCK;  // 32768

    resample_kernel<<<blocks, 256, 0, stream>>>(offsets, inputs4, out4);
}